// Round 1
// 140.764 us; speedup vs baseline: 1.0886x; 1.0886x over previous
//
#include <hip/hip_runtime.h>

// Batched 1D linear interpolation with clamped extrapolation.
// t: [B,N] sorted fp32, v: [B,N] fp32, r: [B,M] fp32 -> out: [B,M] fp32
constexpr int B = 2048;
constexpr int N = 4096;
constexpr int M = 4096;
constexpr int K = 2048;  // buckets; LDS = 32 KB stv + 8 KB lut = 40960 B -> 4 blocks/CU
constexpr int T = 512;   // 512-thread blocks: 4 blocks/CU x 8 waves = 32 waves/CU (100% cap)

__global__ __launch_bounds__(T, 8) void interp_kernel(
    const float* __restrict__ t,
    const float* __restrict__ v,
    const float* __restrict__ r,
    float* __restrict__ out) {
    __shared__ float2 stv[N];   // interleaved (t, v): final fetch is one b64 per point
    __shared__ int lut[K];      // lut[k] = first j with (int)(t[j]*K) >= k; else N

    const int b = blockIdx.x;
    const float* tb = t + (size_t)b * N;
    const float* vb = v + (size_t)b * N;
    const float* rb = r + (size_t)b * M;
    float* ob = out + (size_t)b * M;

    // Stage interleaved (t,v) with coalesced float4 global loads; init lut.
    for (int i = threadIdx.x; i < N / 4; i += T) {
        const float4 t4 = ((const float4*)tb)[i];
        const float4 v4 = ((const float4*)vb)[i];
        stv[4 * i + 0] = make_float2(t4.x, v4.x);
        stv[4 * i + 1] = make_float2(t4.y, v4.y);
        stv[4 * i + 2] = make_float2(t4.z, v4.z);
        stv[4 * i + 3] = make_float2(t4.w, v4.w);
    }
    for (int k = threadIdx.x; k < K; k += T) lut[k] = N;
    __syncthreads();

    // Range-fill: element j claims buckets ((int)(t[j-1]*K), (int)(t[j]*K)].
    // Disjoint ranges -> no races; every covered k written exactly once.
    for (int j = threadIdx.x; j < N; j += T) {
        const float tj = stv[j].x;
        int khi = (int)(tj * K);
        if (khi > K - 1) khi = K - 1;
        int klo = 0;
        if (j > 0) klo = (int)(stv[j - 1].x * K) + 1;
        for (int k = klo; k <= khi; ++k) lut[k] = j;
    }
    __syncthreads();

    const float tfirst = stv[0].x;
    const float vfirst = stv[0].y;
    const float tlast = stv[N - 1].x;
    const float vlast = stv[N - 1].y;

    // Query loop: 8 queries/thread, single pass (512 threads x 2 float4s = M/4).
    // hi bound dropped: t[lut[k+1]] > q always holds (monotone float mul +
    // int trunc), so the t<=q compare stops the scan at the identical index.
    const float4* r4 = (const float4*)rb;
    float4* o4 = (float4*)ob;
    const int ia = threadIdx.x;
    const int ib = ia + T;
    const float4 qa = r4[ia];
    const float4 qb = r4[ib];
    float q[8] = {qa.x, qa.y, qa.z, qa.w, qb.x, qb.y, qb.z, qb.w};
    int lo[8];

    // Phase 1: all 8 lut loads issued together (one b32 each).
    #pragma unroll
    for (int j = 0; j < 8; ++j) {
        int k = (int)(q[j] * K);
        k = k < 0 ? 0 : (k > K - 1 ? K - 1 : k);
        lo[j] = lut[k];
    }
    // Phase 2: branchless scan, 3 predicated steps + rare fallback.
    // Overshoot past N is harmless: safe-index pins N-1, epilogue clamps.
    #pragma unroll
    for (int j = 0; j < 8; ++j) {
        #pragma unroll
        for (int s = 0; s < 3; ++s) {
            const int safe = lo[j] < N - 1 ? lo[j] : N - 1;
            lo[j] += (stv[safe].x <= q[j]) ? 1 : 0;
        }
        while (lo[j] < N && stv[lo[j]].x <= q[j]) ++lo[j];
    }
    // Phase 3: final fetches + interp math (fast rcp instead of IEEE divide).
    float o[8];
    #pragma unroll
    for (int j = 0; j < 8; ++j) {
        const int idx = lo[j] < 1 ? 1 : (lo[j] > N - 1 ? N - 1 : lo[j]);
        const float2 p0 = stv[idx - 1];
        const float2 p1 = stv[idx];
        const float d = p1.x - p0.x;
        const float rden = __builtin_amdgcn_rcpf(d == 0.0f ? 1.0f : d);
        float oo = p0.y + (q[j] - p0.x) * rden * (p1.y - p0.y);
        oo = (q[j] < tfirst) ? vfirst : oo;
        oo = (q[j] > tlast) ? vlast : oo;
        o[j] = oo;
    }
    o4[ia] = make_float4(o[0], o[1], o[2], o[3]);
    o4[ib] = make_float4(o[4], o[5], o[6], o[7]);
}

extern "C" void kernel_launch(void* const* d_in, const int* in_sizes, int n_in,
                              void* d_out, int out_size, void* d_ws, size_t ws_size,
                              hipStream_t stream) {
    const float* t = (const float*)d_in[0];
    const float* v = (const float*)d_in[1];
    const float* r = (const float*)d_in[2];
    float* out = (float*)d_out;
    interp_kernel<<<B, T, 0, stream>>>(t, v, r, out);
}

// Round 2
// 135.704 us; speedup vs baseline: 1.1292x; 1.0373x over previous
//
#include <hip/hip_runtime.h>
#include <float.h>

// Batched 1D linear interpolation with clamped extrapolation.
// t: [B,N] sorted fp32, v: [B,N] fp32, r: [B,M] fp32 -> out: [B,M] fp32
constexpr int B = 2048;
constexpr int N = 4096;
constexpr int M = 4096;
constexpr int K = 4088;  // u16 lut buckets; LDS = 16400 + 16384 + 8176 = 40960 B exactly
constexpr int T = 512;   // 4 blocks/CU x 8 waves = 32 waves/CU

__global__ __launch_bounds__(T, 8) void interp_kernel(
    const float* __restrict__ t,
    const float* __restrict__ v,
    const float* __restrict__ r,
    float* __restrict__ out) {
    // Split arrays: scan reads st[] at 4B stride -> all 32 banks (interleaved
    // float2 made scan .x reads hit only the 16 even banks -> ~2x conflicts).
    __shared__ __align__(16) float st[N + 4];       // st[N..N+1] = +inf sentinels
    __shared__ __align__(16) float sv[N];
    __shared__ unsigned short lut[K];               // lut[k] = first j with (int)(t[j]*K) >= k; else N

    const int b = blockIdx.x;
    const float* tb = t + (size_t)b * N;
    const float* vb = v + (size_t)b * N;
    const float* rb = r + (size_t)b * M;
    float* ob = out + (size_t)b * M;

    // Load this thread's queries FIRST: ~900cy HBM latency hides under
    // staging + lut fill instead of stalling the query phase.
    const float4* r4 = (const float4*)rb;
    const int ia = threadIdx.x;
    const int ib = ia + T;
    const float4 qa = r4[ia];
    const float4 qb = r4[ib];

    // Stage t/v with coalesced float4 loads; init lut; plant sentinels.
    for (int i = threadIdx.x; i < N / 4; i += T) {
        ((float4*)st)[i] = ((const float4*)tb)[i];
        ((float4*)sv)[i] = ((const float4*)vb)[i];
    }
    if (threadIdx.x == 0) { st[N] = FLT_MAX; st[N + 1] = FLT_MAX; }
    for (int k = threadIdx.x; k < K; k += T) lut[k] = (unsigned short)N;
    __syncthreads();

    // Range-fill: element j claims buckets ((int)(t[j-1]*K), (int)(t[j]*K)].
    // Disjoint ranges -> no races; u16 writes are byte-enable safe in LDS.
    for (int j = threadIdx.x; j < N; j += T) {
        const float tj = st[j];
        int khi = (int)(tj * (float)K);
        if (khi > K - 1) khi = K - 1;
        const int klo = (j > 0) ? (int)(st[j - 1] * (float)K) + 1 : 0;
        for (int k = klo; k <= khi; ++k) lut[k] = (unsigned short)j;
    }
    __syncthreads();

    const float tfirst = st[0];
    const float vfirst = sv[0];
    const float tlast = st[N - 1];
    const float vlast = sv[N - 1];

    float q[8] = {qa.x, qa.y, qa.z, qa.w, qb.x, qb.y, qb.z, qb.w};
    int lo[8];

    // Phase 1: all 8 lut loads issued together (u16, random over all banks).
    // Invariant: t[lo-1] <= q (strict bucket math), so scan starts at lo.
    #pragma unroll
    for (int j = 0; j < 8; ++j) {
        int k = (int)(q[j] * (float)K);
        k = k < 0 ? 0 : (k > K - 1 ? K - 1 : k);
        lo[j] = lut[k];
    }
    // Phase 2: sentinel-bounded scan — no clamp, no bounds check.
    // K~N means ~1 point/bucket: 2 predicated steps, fallback ~2% of queries.
    #pragma unroll
    for (int j = 0; j < 8; ++j) {
        lo[j] += (st[lo[j]] <= q[j]) ? 1 : 0;
        lo[j] += (st[lo[j]] <= q[j]) ? 1 : 0;
        while (st[lo[j]] <= q[j]) ++lo[j];
    }
    // Phase 3: final fetches (ds_read2_b32 pairs) + interp math (fast rcp).
    float o[8];
    #pragma unroll
    for (int j = 0; j < 8; ++j) {
        const int idx = lo[j] < 1 ? 1 : (lo[j] > N - 1 ? N - 1 : lo[j]);
        const float t0 = st[idx - 1];
        const float t1 = st[idx];
        const float v0 = sv[idx - 1];
        const float v1 = sv[idx];
        const float d = t1 - t0;
        const float rden = __builtin_amdgcn_rcpf(d == 0.0f ? 1.0f : d);
        float oo = v0 + (q[j] - t0) * rden * (v1 - v0);
        oo = (q[j] < tfirst) ? vfirst : oo;
        oo = (q[j] > tlast) ? vlast : oo;
        o[j] = oo;
    }
    float4* o4 = (float4*)ob;
    o4[ia] = make_float4(o[0], o[1], o[2], o[3]);
    o4[ib] = make_float4(o[4], o[5], o[6], o[7]);
}

extern "C" void kernel_launch(void* const* d_in, const int* in_sizes, int n_in,
                              void* d_out, int out_size, void* d_ws, size_t ws_size,
                              hipStream_t stream) {
    const float* t = (const float*)d_in[0];
    const float* v = (const float*)d_in[1];
    const float* r = (const float*)d_in[2];
    float* out = (float*)d_out;
    interp_kernel<<<B, T, 0, stream>>>(t, v, r, out);
}